// Round 2
// 391.360 us; speedup vs baseline: 1.0253x; 1.0253x over previous
//
#include <hip/hip_runtime.h>

// Problem constants (match reference)
constexpr int B = 4, L = 2048, C = 16, R = 16;
constexpr int M = R * R;       // 256 elements per matrix (1 KB)
constexpr int G = 64;          // chunks per chain
constexpr int S = L / G;       // 32 time steps per chunk
constexpr int LSTRIDE = C * M; // floats between consecutive l (4096)

typedef __attribute__((ext_vector_type(4))) float        f32x4;
typedef __attribute__((ext_vector_type(8))) short        bf16x8;
typedef __attribute__((ext_vector_type(4))) unsigned int u32x4;

// flat offset of element (b, l, c, 0, 0) in [B, L, C, R, R]
__device__ __forceinline__ long mat_off(int b, int l, int c) {
    return (((long)b * L + l) * C + c) * M;
}

// --- bf16 truncation-split helpers -----------------------------------------
// hi16(lo) in low half, hi16(hi) in high half (packed 2x bf16, element order
// matches bf16x8 little-endian element layout: frag elem 2p = low, 2p+1 = high)
__device__ __forceinline__ unsigned pack_hi16(float lo, float hi) {
    return (__float_as_uint(lo) >> 16) | (__float_as_uint(hi) & 0xFFFF0000u);
}
__device__ __forceinline__ float trunc_bf(float v) {
    return __uint_as_float(__float_as_uint(v) & 0xFFFF0000u);
}
__device__ __forceinline__ bf16x8 frag_from(unsigned d0, unsigned d1,
                                            unsigned d2, unsigned d3) {
    u32x4 u = {d0, d1, d2, d3};
    return __builtin_bit_cast(bf16x8, u);
}

// A-operand fragment for mfma_f32_16x16x32_bf16 with concat [A_hi | A_lo]:
// lane (m = lane&15, kg = lane>>4) holds Aop[m][8*kg .. 8*kg+7].
// kg<2 -> truncated-high bf16 of A[m][8*(kg&1)..+7]; kg>=2 -> residual-low.
__device__ __forceinline__ bf16x8 make_a_frag(const f32x4& lo4, const f32x4& hi4,
                                              bool lowk) {
    float a0 = lo4[0], a1 = lo4[1], a2 = lo4[2], a3 = lo4[3];
    float a4 = hi4[0], a5 = hi4[1], a6 = hi4[2], a7 = hi4[3];
    unsigned h0 = pack_hi16(a0, a1), h1 = pack_hi16(a2, a3);
    unsigned h2 = pack_hi16(a4, a5), h3 = pack_hi16(a6, a7);
    unsigned l0 = pack_hi16(a0 - trunc_bf(a0), a1 - trunc_bf(a1));
    unsigned l1 = pack_hi16(a2 - trunc_bf(a2), a3 - trunc_bf(a3));
    unsigned l2 = pack_hi16(a4 - trunc_bf(a4), a5 - trunc_bf(a5));
    unsigned l3 = pack_hi16(a6 - trunc_bf(a6), a7 - trunc_bf(a7));
    return lowk ? frag_from(h0, h1, h2, h3) : frag_from(l0, l1, l2, l3);
}

// Turn a C/D-layout fp32 state Y (lane holds rows 4*(lane>>4)+r, col lane&15)
// into B-operand frags [Y_hi;Y_hi] and [Y_lo;Y_lo] for the next step.
// Source lanes: s0 = 32*(kg&1) + n (rows 8*(kg&1)..+3), s1 = s0+16 (+4..+7).
__device__ __forceinline__ void make_b_frags(const f32x4& y, int s0, int s1,
                                             bf16x8& bh, bf16x8& bl) {
    unsigned yh01 = pack_hi16(y[0], y[1]);
    unsigned yh23 = pack_hi16(y[2], y[3]);
    unsigned yl01 = pack_hi16(y[0] - trunc_bf(y[0]), y[1] - trunc_bf(y[1]));
    unsigned yl23 = pack_hi16(y[2] - trunc_bf(y[2]), y[3] - trunc_bf(y[3]));
    unsigned b0 = (unsigned)__shfl((int)yh01, s0, 64);
    unsigned b1 = (unsigned)__shfl((int)yh23, s0, 64);
    unsigned b2 = (unsigned)__shfl((int)yh01, s1, 64);
    unsigned b3 = (unsigned)__shfl((int)yh23, s1, 64);
    unsigned c0 = (unsigned)__shfl((int)yl01, s0, 64);
    unsigned c1 = (unsigned)__shfl((int)yl23, s0, 64);
    unsigned c2 = (unsigned)__shfl((int)yl01, s1, 64);
    unsigned c3 = (unsigned)__shfl((int)yl23, s1, 64);
    bh = frag_from(b0, b1, b2, b3);
    bl = frag_from(c0, c1, c2, c3);
}

// Pass 1: per-chunk aggregates, one wave per chunk, no LDS, no barriers.
//   Aagg = A_{t_end} ... A_{t_start}; Xagg = local scan value (zero entry state)
// ws slot for chunk: 512 floats = [Aagg(256) | Xagg(256)], element (i,j) at i*16+j.
__global__ __launch_bounds__(256) void pass1_mfma(const float* __restrict__ A,
                                                  const float* __restrict__ X,
                                                  float* __restrict__ ws) {
    const int lane  = threadIdx.x & 63;
    const int chunk = blockIdx.x * 4 + (threadIdx.x >> 6);  // bc * G + g
    const int g  = chunk % G;
    const int bc = chunk / G;
    const int b  = bc / C, c = bc % C;

    const int  mn   = lane & 15;        // A row / B,C col
    const int  kg   = lane >> 4;        // frag k-group 0..3
    const bool lowk = kg < 2;
    const int  kb   = (kg & 1) * 8;     // k base within [0,16)
    const int  s0   = (kg & 1) * 32 + mn;
    const int  s1   = s0 + 16;
    const int  arow = mn * 16 + kb;

    const float* Ap = A + mat_off(b, g * S, c);
    const float* Xp = X + mat_off(b, g * S, c);

    // initial B frags: aggA = I (exact in bf16), aggX = 0
    unsigned id[4];
    #pragma unroll
    for (int r = 0; r < 4; ++r) {
        int k0 = kb + 2 * r;
        unsigned v = 0u;
        if (k0 == mn)     v |= 0x3F80u;
        if (k0 + 1 == mn) v |= 0x3F800000u;
        id[r] = v;
    }
    bf16x8 BAh = frag_from(id[0], id[1], id[2], id[3]);
    bf16x8 BAl = frag_from(0, 0, 0, 0);
    bf16x8 BXh = frag_from(0, 0, 0, 0);
    bf16x8 BXl = BXh;

    f32x4 aLo = *(const f32x4*)(Ap + arow);
    f32x4 aHi = *(const f32x4*)(Ap + arow + 4);
    f32x4 xc;
    #pragma unroll
    for (int r = 0; r < 4; ++r) xc[r] = Xp[(4 * kg + r) * 16 + mn];

    f32x4 accA, accX;
    const f32x4 zero = {0.f, 0.f, 0.f, 0.f};
    for (int t = 0; t < S; ++t) {
        f32x4 aLoN, aHiN, xcN;
        if (t < S - 1) {                       // prefetch next step (1-deep)
            const float* An = Ap + (t + 1) * LSTRIDE;
            const float* Xn = Xp + (t + 1) * LSTRIDE;
            aLoN = *(const f32x4*)(An + arow);
            aHiN = *(const f32x4*)(An + arow + 4);
            #pragma unroll
            for (int r = 0; r < 4; ++r) xcN[r] = Xn[(4 * kg + r) * 16 + mn];
        }
        const bf16x8 Af = make_a_frag(aLo, aHi, lowk);
        // aggA = A_t @ aggA ; aggX = A_t @ aggX + X_t (X exact via C operand)
        accA = __builtin_amdgcn_mfma_f32_16x16x32_bf16(Af, BAh, zero, 0, 0, 0);
        accA = __builtin_amdgcn_mfma_f32_16x16x32_bf16(Af, BAl, accA, 0, 0, 0);
        accX = __builtin_amdgcn_mfma_f32_16x16x32_bf16(Af, BXh, xc,   0, 0, 0);
        accX = __builtin_amdgcn_mfma_f32_16x16x32_bf16(Af, BXl, accX, 0, 0, 0);
        if (t < S - 1) {
            make_b_frags(accA, s0, s1, BAh, BAl);
            make_b_frags(accX, s0, s1, BXh, BXl);
            aLo = aLoN; aHi = aHiN; xc = xcN;
        }
    }
    float* slot = ws + (long)chunk * (2 * M);
    #pragma unroll
    for (int r = 0; r < 4; ++r) {
        slot[(4 * kg + r) * 16 + mn]     = accA[r];
        slot[M + (4 * kg + r) * 16 + mn] = accX[r];
    }
}

// Pass 2: sequential scan over the G chunk aggregates of one chain.
// Writes the EXCLUSIVE Y-carry for chunk g in-place over its Xagg slot.
// (unchanged structure; + 1-deep prefetch of the next slot to hide latency)
__global__ __launch_bounds__(256) void pass2_scan(float* __restrict__ ws) {
    const int bc  = blockIdx.x;           // 0 .. B*C-1
    const int tid = threadIdx.x;
    const int i = tid >> 4, j = tid & 15;

    __shared__ float sAg[M];
    __shared__ float carry[M];
    carry[tid] = 0.0f;

    float* base = ws + (long)bc * G * (2 * M);
    float curA = base[tid];
    float curX = base[M + tid];
    for (int g = 0; g < G; ++g) {
        float* slot = base + (long)g * (2 * M);
        float nA = 0.f, nX = 0.f;
        if (g < G - 1) {                  // prefetch next slot (reads original
            nA = slot[2 * M + tid];       //  Xagg before iter g+1 overwrites it)
            nX = slot[2 * M + M + tid];
        }
        sAg[tid] = curA;                  // Aagg_g
        const float xg  = curX;           // Xagg_g
        const float old = carry[tid];     // own element (exclusive carry)
        __syncthreads();                  // sAg visible; prev carry writes done
        float acc = xg;
        #pragma unroll
        for (int k = 0; k < 16; ++k)
            acc += sAg[(i << 4) + k] * carry[(k << 4) + j];
        slot[M + tid] = old;              // exclusive Y-carry out
        __syncthreads();                  // all reads of old carry done
        carry[tid] = acc;
        __syncthreads();
        curA = nA; curX = nX;
    }
}

// Pass 3: re-run the recurrence within each chunk from its exclusive carry.
// One wave per chunk, no LDS, no barriers; coalesced stores in C-frag layout.
__global__ __launch_bounds__(256) void pass3_mfma(const float* __restrict__ A,
                                                  const float* __restrict__ X,
                                                  const float* __restrict__ ws,
                                                  float* __restrict__ out) {
    const int lane  = threadIdx.x & 63;
    const int chunk = blockIdx.x * 4 + (threadIdx.x >> 6);  // bc * G + g
    const int g  = chunk % G;
    const int bc = chunk / G;
    const int b  = bc / C, c = bc % C;

    const int  mn   = lane & 15;
    const int  kg   = lane >> 4;
    const bool lowk = kg < 2;
    const int  kb   = (kg & 1) * 8;
    const int  s0   = (kg & 1) * 32 + mn;
    const int  s1   = s0 + 16;
    const int  arow = mn * 16 + kb;

    const float* Ap = A + mat_off(b, g * S, c);
    const float* Xp = X + mat_off(b, g * S, c);
    float*       Op = out + mat_off(b, g * S, c);

    const float* slot = ws + (long)chunk * (2 * M);
    f32x4 Y;
    #pragma unroll
    for (int r = 0; r < 4; ++r) Y[r] = slot[M + (4 * kg + r) * 16 + mn];

    bf16x8 Bh, Bl;
    make_b_frags(Y, s0, s1, Bh, Bl);

    f32x4 aLo = *(const f32x4*)(Ap + arow);
    f32x4 aHi = *(const f32x4*)(Ap + arow + 4);
    f32x4 xc;
    #pragma unroll
    for (int r = 0; r < 4; ++r) xc[r] = Xp[(4 * kg + r) * 16 + mn];

    for (int t = 0; t < S; ++t) {
        f32x4 aLoN, aHiN, xcN;
        if (t < S - 1) {
            const float* An = Ap + (t + 1) * LSTRIDE;
            const float* Xn = Xp + (t + 1) * LSTRIDE;
            aLoN = *(const f32x4*)(An + arow);
            aHiN = *(const f32x4*)(An + arow + 4);
            #pragma unroll
            for (int r = 0; r < 4; ++r) xcN[r] = Xn[(4 * kg + r) * 16 + mn];
        }
        const bf16x8 Af = make_a_frag(aLo, aHi, lowk);
        f32x4 acc = __builtin_amdgcn_mfma_f32_16x16x32_bf16(Af, Bh, xc, 0, 0, 0);
        acc = __builtin_amdgcn_mfma_f32_16x16x32_bf16(Af, Bl, acc, 0, 0, 0);
        float* o = Op + t * LSTRIDE;
        #pragma unroll
        for (int r = 0; r < 4; ++r) o[(4 * kg + r) * 16 + mn] = acc[r];
        if (t < S - 1) {
            make_b_frags(acc, s0, s1, Bh, Bl);
            aLo = aLoN; aHi = aHiN; xc = xcN;
        }
    }
}

extern "C" void kernel_launch(void* const* d_in, const int* in_sizes, int n_in,
                              void* d_out, int out_size, void* d_ws, size_t ws_size,
                              hipStream_t stream) {
    const float* A = (const float*)d_in[0];
    const float* X = (const float*)d_in[1];
    float* out = (float*)d_out;
    float* ws  = (float*)d_ws;   // needs B*C*G*512 floats = 8 MB

    pass1_mfma<<<B * C * G / 4, 256, 0, stream>>>(A, X, ws);
    pass2_scan<<<B * C, 256, 0, stream>>>(ws);
    pass3_mfma<<<B * C * G / 4, 256, 0, stream>>>(A, X, ws, out);
}